// Round 16
// baseline (739.598 us; speedup 1.0000x reference)
//
#include <hip/hip_runtime.h>
#include <stdint.h>

// BitNet b1.58 column-parallel linear:
//   y[m,n] = (sum_k qx[m,k]*qw[n,k]) * inv_sx[m] * inv_sw + bias[n]
// M=8192 (B*S), N=16384 (D_OUT), K=4096 (D_IN)
//
// This round: PRE-PACKED fragment layout. Quant kernels emit
//   packed[rowblk][kstep][lane] (16B chunks), rowblk=row/16, kstep=k/64,
//   lane l <-> (row = rowblk*16 + (l&15), kbytes = kstep*64 + (l>>4)*16 .. +16)
// which is byte-identical to the MFMA fragment mapping verified in rounds 1-15.
// The GEMM then loads fragments with single coalesced global_load_dwordx4
// (lane stride 16B) -> ZERO LDS, ZERO barriers in the GEMM.

#define M_ROWS 8192
#define N_COLS 16384
#define K_DIM  4096
#define NT     (K_DIM / 64)   // 64 K-steps of 64 bytes

typedef int v4i __attribute__((ext_vector_type(4)));

// ---------------- workspace layout (sizes unchanged; layouts packed) ----------------
#define WS_PARTIALS 0
#define WS_PARAMS   8192
#define WS_INVSX    8448
#define WS_QX       41216
#define WS_QW       (41216 + 33554432)
#define WS_NEED     ((size_t)WS_QW + 67108864)

#define QP 1028   // padded ints per row in the LDS transpose tile (1024 + 4)

__device__ __forceinline__ int quant_act1(float v, float s) {
    float q = rintf(v * s);               // round-half-even, matches jnp.round
    q = fminf(127.0f, fmaxf(-128.0f, q));
    return (int)q;
}
__device__ __forceinline__ int quant_w1(float v, float s) {
    float q = rintf(v * s);
    q = fminf(1.0f, fmaxf(-1.0f, q));
    return (int)q;
}

// ---------------- fused: act quant+pack (blocks 0..511) + weight abs-sum partials
// (blocks 512..2559) ----------------
__global__ __launch_bounds__(256) void fused_quant_kernel(const float* __restrict__ x,
                                                          int8_t* __restrict__ qxp,
                                                          float* __restrict__ inv_sx,
                                                          const float* __restrict__ w,
                                                          float* __restrict__ partials) {
    const int t = threadIdx.x;
    if (blockIdx.x < 512) {
        // ---- act: 16 rows per block; max -> quant to LDS tile -> packed store ----
        __shared__ int qtile[16 * QP];                 // 65792 B
        __shared__ float wmax[16][4];
        __shared__ float scales[16];
        const int rowbase = blockIdx.x * 16;
        const int wv = t >> 6, lane = t & 63;

        // pass 1: per-row absmax (coalesced reads)
#pragma unroll 1
        for (int r = 0; r < 16; ++r) {
            const float4* xr4 = (const float4*)(x + (size_t)(rowbase + r) * K_DIM);
            float m = 0.0f;
#pragma unroll
            for (int i = 0; i < 4; ++i) {
                float4 v = xr4[t + 256 * i];
                m = fmaxf(m, fmaxf(fmaxf(fabsf(v.x), fabsf(v.y)),
                                   fmaxf(fabsf(v.z), fabsf(v.w))));
            }
#pragma unroll
            for (int off = 32; off > 0; off >>= 1) m = fmaxf(m, __shfl_xor(m, off));
            if (lane == 0) wmax[r][wv] = m;
        }
        __syncthreads();
        if (t < 16) {
            float m = fmaxf(fmaxf(wmax[t][0], wmax[t][1]), fmaxf(wmax[t][2], wmax[t][3]));
            m = fmaxf(m, 1e-5f);                       // clip(max, EPS)
            const float scale = 127.0f / m;
            scales[t] = scale;
            inv_sx[rowbase + t] = 1.0f / scale;
        }
        __syncthreads();

        // pass 2: quantize (L2-hot re-read) into row-major LDS tile
#pragma unroll 1
        for (int r = 0; r < 16; ++r) {
            const float4* xr4 = (const float4*)(x + (size_t)(rowbase + r) * K_DIM);
            const float s = scales[r];
#pragma unroll
            for (int i = 0; i < 4; ++i) {
                float4 v = xr4[t + 256 * i];
                int b0 = quant_act1(v.x, s) & 255;
                int b1 = quant_act1(v.y, s) & 255;
                int b2 = quant_act1(v.z, s) & 255;
                int b3 = quant_act1(v.w, s) & 255;
                qtile[r * QP + t + 256 * i] = b0 | (b1 << 8) | (b2 << 16) | (b3 << 24);
            }
        }
        __syncthreads();

        // pass 3: pack to global — lane l: row l&15, sub l>>4; wave wv covers 16 ksteps
        int8_t* out = qxp + (size_t)blockIdx.x * 65536;
        const int rr = lane & 15, sub = lane >> 4;
#pragma unroll 1
        for (int ks = 0; ks < 16; ++ks) {
            const int kstep = wv * 16 + ks;
            v4i c = *(const v4i*)&qtile[rr * QP + kstep * 16 + sub * 4];
            *(v4i*)(out + (size_t)kstep * 1024 + lane * 16) = c;   // 1KB/instr coalesced
        }
    } else {
        // ---- weight abs-sum partial (deterministic, unchanged) ----
        const int pb = blockIdx.x - 512;              // 0..2047
        const size_t base = (size_t)pb * 8192;        // float4 units
        const float4* w4 = (const float4*)w;
        float s = 0.0f;
#pragma unroll 8
        for (int i = 0; i < 32; ++i) {
            float4 v = w4[base + (size_t)i * 256 + t];
            s += fabsf(v.x) + fabsf(v.y) + fabsf(v.z) + fabsf(v.w);
        }
#pragma unroll
        for (int off = 32; off > 0; off >>= 1) s += __shfl_xor(s, off);
        __shared__ float wp[4];
        if ((t & 63) == 0) wp[t >> 6] = s;
        __syncthreads();
        if (t == 0) partials[pb] = (wp[0] + wp[1]) + (wp[2] + wp[3]);
    }
}

__global__ __launch_bounds__(256) void wfinal_kernel(const float* __restrict__ partials,
                                                     float* __restrict__ params) {
    __shared__ double sh[256];
    const int t = threadIdx.x;
    double s = 0.0;
    for (int i = t; i < 2048; i += 256) s += (double)partials[i];
    sh[t] = s;
    __syncthreads();
    for (int off = 128; off > 0; off >>= 1) {
        if (t < off) sh[t] += sh[t + off];
        __syncthreads();
    }
    if (t == 0) {
        float mean = (float)(sh[0] / 67108864.0);
        mean = fmaxf(mean, 1e-5f);        // clip(mean, EPS)
        float scale = 1.0f / mean;        // scale_w
        params[0] = scale;
        params[1] = 1.0f / scale;         // inv_sw
    }
}

// ---------------- weight quant + pack: 16 rows/block, ternary, packed layout ----------
__global__ __launch_bounds__(256) void w_quant_pack_kernel(const float* __restrict__ w,
                                                           int8_t* __restrict__ qwp,
                                                           const float* __restrict__ params) {
    __shared__ int qtile[16 * QP];
    const int t = threadIdx.x;
    const int wv = t >> 6, lane = t & 63;
    const int rowbase = blockIdx.x * 16;
    const float s = params[0];

#pragma unroll 1
    for (int r = 0; r < 16; ++r) {
        const float4* wr4 = (const float4*)(w + (size_t)(rowbase + r) * K_DIM);
#pragma unroll
        for (int i = 0; i < 4; ++i) {
            float4 v = wr4[t + 256 * i];
            int b0 = quant_w1(v.x, s) & 255;
            int b1 = quant_w1(v.y, s) & 255;
            int b2 = quant_w1(v.z, s) & 255;
            int b3 = quant_w1(v.w, s) & 255;
            qtile[r * QP + t + 256 * i] = b0 | (b1 << 8) | (b2 << 16) | (b3 << 24);
        }
    }
    __syncthreads();

    int8_t* out = qwp + (size_t)blockIdx.x * 65536;
    const int rr = lane & 15, sub = lane >> 4;
#pragma unroll 1
    for (int ks = 0; ks < 16; ++ks) {
        const int kstep = wv * 16 + ks;
        v4i c = *(const v4i*)&qtile[rr * QP + kstep * 16 + sub * 4];
        *(v4i*)(out + (size_t)kstep * 1024 + lane * 16) = c;
    }
}

// ---------------- int8 GEMM: NO-LDS, packed-fragment direct register loads ----------
// 256x128 tile, 4 waves (2M x 2N), per-wave 128x64, mfma_i32_16x16x64_i8.
// Per K-step: 12 coalesced global_load_dwordx4 (lane*16 stride — one fragment each)
// + 32 MFMA. Reg-dbuf P/Q one step ahead; single counted vmcnt(12)/step; no barriers,
// no LDS, no DS-pipe traffic at all. A frags shared by wc-pair, B by wr-pair -> L1;
// panels L2-resident via bn-fast XCD swizzle.
// Ledger: prologue LOAD(P,0),LOAD(Q,1),VM(12) proves t=0. Steady (even t):
// { MFMA(P) | LOAD(P, t+2) (WAR keeps order after MFMA) | VM(12) -> proves t+1 }.
// Tail: MFMA(P=62) | VM(0) -> 63 proven | MFMA(Q=63).
__global__ __launch_bounds__(256, 2) void gemm_i8_kernel(const int8_t* __restrict__ qxp,
                                                         const int8_t* __restrict__ qwp,
                                                         const float* __restrict__ inv_sx,
                                                         const float* __restrict__ params,
                                                         const float* __restrict__ bias,
                                                         float* __restrict__ y) {
    const int tid = threadIdx.x;
    const int lane = tid & 63;
    const int w = tid >> 6;           // wave 0..3
    const int wr = w >> 1;            // 0..1  (M half)
    const int wc = w & 1;             // 0..1  (N half)

    // XCD-aware bijective swizzle: 4096 blocks, 8 XCDs; bn-fast (A panel L2-resident)
    const int bid = blockIdx.x;
    const int swz = (bid & 7) * 512 + (bid >> 3);
    const int bn = swz & 127;         // 128 n-blocks
    const int bm = swz >> 7;          // 32 m-blocks

    const int arow0 = bm * 256;
    const int bcol0 = bn * 128;

    // fragment base pointers: rowblk stride 65536 B, kstep stride 1024 B, lane*16
    const int arb = (arow0 >> 4) + wr * 8;    // 8 A rowblks per wave
    const int brb = (bcol0 >> 4) + wc * 4;    // 4 B rowblks per wave
    const int8_t* pA = qxp + (size_t)arb * 65536 + lane * 16;
    const int8_t* pB = qwp + (size_t)brb * 65536 + lane * 16;

    v4i aP[8], bP[4], aQ[8], bQ[4];
    v4i acc[8][4];
#pragma unroll
    for (int i = 0; i < 8; ++i)
#pragma unroll
        for (int j = 0; j < 4; ++j) acc[i][j] = (v4i){0, 0, 0, 0};

#define LOADSET(A_, B_, t)                                                     \
    do {                                                                       \
        _Pragma("unroll") for (int _i = 0; _i < 8; ++_i)                       \
            A_[_i] = *(const v4i*)(pA + (size_t)_i * 65536 + (size_t)(t) * 1024); \
        _Pragma("unroll") for (int _j = 0; _j < 4; ++_j)                       \
            B_[_j] = *(const v4i*)(pB + (size_t)_j * 65536 + (size_t)(t) * 1024); \
    } while (0)

#define MFMA32(A_, B_)                                                         \
    do {                                                                       \
        __builtin_amdgcn_s_setprio(1);                                         \
        _Pragma("unroll") for (int _i = 0; _i < 8; ++_i)                       \
            _Pragma("unroll") for (int _j = 0; _j < 4; ++_j)                   \
                acc[_i][_j] = __builtin_amdgcn_mfma_i32_16x16x64_i8(           \
                    A_[_i], B_[_j], acc[_i][_j], 0, 0, 0);                     \
        __builtin_amdgcn_s_setprio(0);                                         \
    } while (0)

#define VM(NSTR)                                                               \
    do {                                                                       \
        asm volatile("s_waitcnt vmcnt(" NSTR ")" ::: "memory");                \
        __builtin_amdgcn_sched_barrier(0);                                     \
    } while (0)

    // prologue
    LOADSET(aP, bP, 0);
    LOADSET(aQ, bQ, 1);
    VM("12");                         // t=0 proven (t=1's 12 in flight)

    // main loop: j=0..30 covers t=0..61, loads t=2..63
#pragma unroll 1
    for (int j = 0; j < 31; ++j) {
        const int tb = 2 * j;
        MFMA32(aP, bP);               // compute t=tb
        LOADSET(aP, bP, tb + 2);      // WAR after MFMA; refill P
        VM("12");                     // proves t=tb+1 (24 outstanding -> keep newest 12)
        MFMA32(aQ, bQ);               // compute t=tb+1
        LOADSET(aQ, bQ, tb + 3);
        VM("12");                     // proves t=tb+2
    }
    // tail: t=62, 63
    MFMA32(aP, bP);                   // t=62
    VM("0");                          // t=63 proven
    MFMA32(aQ, bQ);                   // t=63

    // epilogue: y = acc * inv_sx[row] * inv_sw + bias[col]  (verified 16x16 C/D layout)
    const float invsw = params[1];
    const int rl = (lane >> 4) * 4;
    const int lrow = lane & 15;
#pragma unroll
    for (int i = 0; i < 8; ++i) {
        const int grow_base = arow0 + wr * 128 + i * 16 + rl;
        float isx[4];
#pragma unroll
        for (int r = 0; r < 4; ++r) isx[r] = inv_sx[grow_base + r] * invsw;
#pragma unroll
        for (int j = 0; j < 4; ++j) {
            const int gcol = bcol0 + wc * 64 + j * 16 + lrow;
            const float bb = bias[gcol];
#pragma unroll
            for (int r = 0; r < 4; ++r) {
                y[(size_t)(grow_base + r) * N_COLS + gcol] =
                    (float)acc[i][j][r] * isx[r] + bb;
            }
        }
    }
#undef LOADSET
#undef MFMA32
#undef VM
}

// ---------------- launch ----------------
extern "C" void kernel_launch(void* const* d_in, const int* in_sizes, int n_in,
                              void* d_out, int out_size, void* d_ws, size_t ws_size,
                              hipStream_t stream) {
    const float* x    = (const float*)d_in[0];
    const float* wt   = (const float*)d_in[1];
    const float* bias = (const float*)d_in[2];
    float* y = (float*)d_out;

    if (ws_size < WS_NEED) return;

    char* ws = (char*)d_ws;
    float* partials = (float*)(ws + WS_PARTIALS);
    float* params   = (float*)(ws + WS_PARAMS);
    float* inv_sx   = (float*)(ws + WS_INVSX);
    int8_t* qxp = (int8_t*)(ws + WS_QX);
    int8_t* qwp = (int8_t*)(ws + WS_QW);

    hipLaunchKernelGGL(fused_quant_kernel, dim3(2560), dim3(256), 0, stream,
                       x, qxp, inv_sx, wt, partials);
    hipLaunchKernelGGL(wfinal_kernel,      dim3(1),    dim3(256), 0, stream, partials, params);
    hipLaunchKernelGGL(w_quant_pack_kernel,dim3(1024), dim3(256), 0, stream, wt, qwp, params);
    hipLaunchKernelGGL(gemm_i8_kernel,     dim3(4096), dim3(256), 0, stream,
                       qxp, qwp, inv_sx, params, bias, y);
}